// Round 15
// baseline (593.426 us; speedup 1.0000x reference)
//
#include <hip/hip_runtime.h>

#define VQ_B 32
#define VQ_D 64
#define VQ_L 4096
#define VQ_N 1024
#define VQ_R (VQ_B * VQ_L)            /* 131072 rows */
#define VQ_ZQ ((size_t)VQ_R * VQ_D)   /* 8388608 z_q elements */
#define MAIN_BLOCK 256
#define MAIN_GRID (VQ_R / MAIN_BLOCK) /* 512 */
#define CAND_CAP 16
#define EPSREL 4.5e-3f                /* >= 2^-8 bf16 unit roundoff */
#define RT 4                          /* row-tiles per wave (64 rows) */
#define NSEG 4                        /* code segments (grid.y) */
#define SEGC (VQ_N / NSEG)            /* 256 codes per segment */
#define NCT (SEGC / 16)               /* 16 code-tiles per segment */

typedef __attribute__((ext_vector_type(16))) float f32x16;
typedef __attribute__((ext_vector_type(8)))  short short8;   /* 8 bf16 */
typedef __attribute__((ext_vector_type(4)))  float f32x4;
typedef __attribute__((ext_vector_type(4)))  unsigned int u32x4;

/* ---------- monotone float<->u32 keys ---------- */
__device__ __forceinline__ unsigned fmono(float x) {
    unsigned u = __builtin_bit_cast(unsigned, x);
    return (u & 0x80000000u) ? ~u : (u | 0x80000000u);
}
__device__ __forceinline__ float fmono_dec(unsigned k) {
    unsigned u = (k & 0x80000000u) ? (k & 0x7FFFFFFFu) : ~k;
    return __builtin_bit_cast(float, u);
}
__device__ __forceinline__ unsigned short f2bf(float x) {
    __bf16 h = (__bf16)x;  /* RNE */
    return __builtin_bit_cast(unsigned short, h);
}

/* ---------- validated numpy-pairwise norm machinery ---------- */
#define ZVE(i) ((i) < 16 ? zvA[(i) & 15] : (i) < 32 ? zvB[(i) & 15] \
               : (i) < 48 ? zvC[(i) & 15] : zvD[(i) & 15])
#define SQB(x) ({ float s_ = (x) * (x); asm volatile("" : "+v"(s_)); s_; })
#define NP_PAIRWISE64_SQ(dst)                                                  \
    do {                                                                       \
        float r0 = SQB(ZVE(0)), r1 = SQB(ZVE(1)), r2 = SQB(ZVE(2)),            \
              r3 = SQB(ZVE(3)), r4 = SQB(ZVE(4)), r5 = SQB(ZVE(5)),            \
              r6 = SQB(ZVE(6)), r7 = SQB(ZVE(7));                              \
        _Pragma("unroll")                                                      \
        for (int i_ = 1; i_ < 8; ++i_) {                                       \
            r0 += SQB(ZVE(8 * i_ + 0)); r1 += SQB(ZVE(8 * i_ + 1));            \
            r2 += SQB(ZVE(8 * i_ + 2)); r3 += SQB(ZVE(8 * i_ + 3));            \
            r4 += SQB(ZVE(8 * i_ + 4)); r5 += SQB(ZVE(8 * i_ + 5));            \
            r6 += SQB(ZVE(8 * i_ + 6)); r7 += SQB(ZVE(8 * i_ + 7));            \
        }                                                                      \
        dst = ((r0 + r1) + (r2 + r3)) + ((r4 + r5) + (r6 + r7));               \
    } while (0)

/* ---------- init: rowcnt=0, nEmax=0 ---------- */
__global__ void vq_init(unsigned* __restrict__ rowcnt, unsigned* __restrict__ nEmax) {
    const int i = blockIdx.x * blockDim.x + threadIdx.x;
    if (i < VQ_R) rowcnt[i] = 0u;
    if (i == 0) *nEmax = 0u;
}

/* ---------- prep emb: exact nE (np chain), emb->bf16, nEmax ---------- */
__global__ void vq_prep_emb(const float* __restrict__ emb, float* __restrict__ nE,
                            unsigned short* __restrict__ emb_bf,
                            unsigned* __restrict__ nEmax) {
    const int c = blockIdx.x * blockDim.x + threadIdx.x;
    if (c >= VQ_N) return;
    const float* ec = emb + (c << 6);
    f32x16 zvA, zvB, zvC, zvD;
#pragma unroll
    for (int d = 0; d < 16; ++d) {
        zvA[d] = ec[d];
        zvB[d] = ec[d + 16];
        zvC[d] = ec[d + 32];
        zvD[d] = ec[d + 48];
    }
    float s;
    NP_PAIRWISE64_SQ(s);
    nE[c] = s;
    atomicMax(nEmax, fmono(s));
#pragma unroll
    for (int d = 0; d < 64; ++d) emb_bf[(c << 6) + d] = f2bf(ec[d]);
}

/* ---------- prep z: bf16 rows + per-row margin (runs after prep_emb) ----
   mrg = 8*EPSREL*sqrt(||z||^2 * nEmax) + 2e-4 — the rigorous local-margin:
   |g~-g| <= 4u*||z||*||e|| (u=2^-8), emission needs 2x that + reorder slack. */
__global__ __launch_bounds__(256) void vq_prep_z(
    const float* __restrict__ z, const unsigned* __restrict__ nEmax,
    unsigned short* __restrict__ z_bf, float* __restrict__ mrg) {
    const int r = blockIdx.x * 256 + threadIdx.x;
    const int b = r >> 12;
    const int l = r & (VQ_L - 1);
    const float* zp = z + ((size_t)b << 18) + l;
    unsigned short* o = z_bf + ((size_t)r << 6);
    float s = 0.0f;
#pragma unroll
    for (int j8 = 0; j8 < 8; ++j8) {
        unsigned w[4];
#pragma unroll
        for (int p = 0; p < 4; ++p) {
            const float v0 = zp[(size_t)(j8 * 8 + 2 * p) << 12];
            const float v1 = zp[(size_t)(j8 * 8 + 2 * p + 1) << 12];
            s = __builtin_fmaf(v0, v0, s);
            s = __builtin_fmaf(v1, v1, s);
            w[p] = (unsigned)f2bf(v0) | ((unsigned)f2bf(v1) << 16);
        }
        *(u32x4*)(o + j8 * 8) = (u32x4){w[0], w[1], w[2], w[3]};
    }
    const float nem = fmono_dec(*nEmax);
    mrg[r] = 8.0f * EPSREL * sqrtf(s * nem) + 2e-4f;
}

/* ---------- single-pass MFMA screen ----------
   Grid (512, NSEG). Block: 256 rows x SEGC=256 codes, emb segment staged
   in LDS chunk-major ebS[j][row][8] (b-reads: ds_read_b128, slot=(row&7)
   -> 8 lanes/16B slot = bandwidth-optimal, no L2 round trips). Sweep A:
   per-row min of g~ over the block's codes; butterfly allreduce across
   the 16 cl lanes; thr = min + mrg[row] (in-place in mt). Sweep B: same
   MFMA sequence on same register/LDS inputs -> bit-identical g~; emit
   codes with g~ <= thr. Local-margin rigor: true exact-argmin c* (in
   segment s*) has g~(c*) <= m_s* + mrg, so it is always emitted by its
   own segment's block. Candidate order across blocks is nondeterministic
   but the stored SET (cnt<=CAP) is, and vq_exact's (D,c)-key min is
   order-independent -> deterministic output. */
__global__ __launch_bounds__(256, 4) void vq_screen(
    const unsigned short* __restrict__ z_bf, const unsigned short* __restrict__ emb_bf,
    const float* __restrict__ nE, const float* __restrict__ mrg,
    unsigned* __restrict__ rowcnt, unsigned short* __restrict__ candrow) {
    __shared__ unsigned short ebS[8 * SEGC * 8];  /* 32 KB, chunk-major */
    __shared__ float neS[SEGC];                   /* 1 KB */
    const int tid = threadIdx.x;
    const int c0 = blockIdx.y * SEGC;             /* block-uniform -> scalar */

    /* stage: 2048 16B chunks; global reads linear/coalesced */
    for (int q = tid; q < SEGC * 8; q += 256) {
        const short8 v = *(const short8*)(emb_bf + ((size_t)c0 << 6) + q * 8);
        *(short8*)(ebS + ((q & 7) * SEGC + (q >> 3)) * 8) = v;
    }
    neS[tid] = nE[c0 + tid];
    __syncthreads();

    const int w = tid >> 6, lane = tid & 63;
    const int cl = lane & 15, grp = lane >> 4;
    const int rowbase = blockIdx.x * 256 + w * (16 * RT);

    short8 a0[RT], a1[RT];
#pragma unroll
    for (int t = 0; t < RT; ++t) {
        const unsigned short* za = z_bf + ((size_t)(rowbase + t * 16 + cl) << 6) + grp * 8;
        a0[t] = *(const short8*)(za);
        a1[t] = *(const short8*)(za + 32);
    }

    int row_r[RT][4];
#pragma unroll
    for (int t = 0; t < RT; ++t)
#pragma unroll
        for (int reg = 0; reg < 4; ++reg)
            row_r[t][reg] = rowbase + t * 16 + grp * 4 + reg;

    float mt[RT][4];
#pragma unroll
    for (int t = 0; t < RT; ++t)
#pragma unroll
        for (int reg = 0; reg < 4; ++reg) mt[t][reg] = __builtin_inff();

    /* ---- sweep A: per-row min over this segment's codes ---- */
#pragma unroll 2
    for (int ct = 0; ct < NCT; ++ct) {
        const int cr = ct * 16 + cl;
        const short8 b0 = *(const short8*)(ebS + (grp * SEGC + cr) * 8);
        const short8 b1 = *(const short8*)(ebS + ((grp + 4) * SEGC + cr) * 8);
        const float ne = neS[cr];
        f32x4 acc[RT];
#pragma unroll
        for (int t = 0; t < RT; ++t) {
            acc[t] = (f32x4){0.0f, 0.0f, 0.0f, 0.0f};
            acc[t] = __builtin_amdgcn_mfma_f32_16x16x32_bf16(a0[t], b0, acc[t], 0, 0, 0);
            acc[t] = __builtin_amdgcn_mfma_f32_16x16x32_bf16(a1[t], b1, acc[t], 0, 0, 0);
        }
#pragma unroll
        for (int t = 0; t < RT; ++t)
#pragma unroll
            for (int reg = 0; reg < 4; ++reg) {
                const float g = __builtin_fmaf(-2.0f, acc[t][reg], ne);
                mt[t][reg] = fminf(mt[t][reg], g);
            }
    }

    /* ---- allreduce across cl lanes, thr = min + mrg (in-place) ---- */
#pragma unroll
    for (int t = 0; t < RT; ++t)
#pragma unroll
        for (int reg = 0; reg < 4; ++reg) {
            float v = mt[t][reg];
            v = fminf(v, __shfl_xor(v, 1));
            v = fminf(v, __shfl_xor(v, 2));
            v = fminf(v, __shfl_xor(v, 4));
            v = fminf(v, __shfl_xor(v, 8));
            mt[t][reg] = v + mrg[row_r[t][reg]];
        }

    /* ---- sweep B: identical g~ bits; emit survivors ---- */
#pragma unroll 2
    for (int ct = 0; ct < NCT; ++ct) {
        const int cr = ct * 16 + cl;
        const short8 b0 = *(const short8*)(ebS + (grp * SEGC + cr) * 8);
        const short8 b1 = *(const short8*)(ebS + ((grp + 4) * SEGC + cr) * 8);
        const float ne = neS[cr];
        f32x4 acc[RT];
#pragma unroll
        for (int t = 0; t < RT; ++t) {
            acc[t] = (f32x4){0.0f, 0.0f, 0.0f, 0.0f};
            acc[t] = __builtin_amdgcn_mfma_f32_16x16x32_bf16(a0[t], b0, acc[t], 0, 0, 0);
            acc[t] = __builtin_amdgcn_mfma_f32_16x16x32_bf16(a1[t], b1, acc[t], 0, 0, 0);
        }
#pragma unroll
        for (int t = 0; t < RT; ++t)
#pragma unroll
            for (int reg = 0; reg < 4; ++reg) {
                const float g = __builtin_fmaf(-2.0f, acc[t][reg], ne);
                if (g <= mt[t][reg]) {
                    const unsigned idx = atomicAdd(&rowcnt[row_r[t][reg]], 1u);
                    if (idx < CAND_CAP)
                        candrow[(size_t)row_r[t][reg] * CAND_CAP + idx] =
                            (unsigned short)(c0 + cr);
                }
            }
    }
}

/* ---------- exact phase: bit-exact D for survivors, (D,c)-min ---------- */
__global__ __launch_bounds__(MAIN_BLOCK) void vq_exact(
    const float* __restrict__ z, const float* __restrict__ emb,
    const float* __restrict__ nE, const unsigned* __restrict__ rowcnt,
    const unsigned short* __restrict__ candrow, float* __restrict__ out,
    float* __restrict__ partials) {
    const int r = blockIdx.x * MAIN_BLOCK + threadIdx.x;
    const int b = r >> 12;
    const int l = r & (VQ_L - 1);
    const float* zp = z + ((size_t)b << 18) + l;

    /* szz: numpy pairwise (8 accs, d=8i+j ascending, squares pre-rounded) */
    float a8[8];
#pragma unroll
    for (int j = 0; j < 8; ++j) {
        const float v = zp[(size_t)j << 12];
        float s = v * v;
        asm volatile("" : "+v"(s));
        a8[j] = s;
    }
#pragma unroll
    for (int i = 1; i < 8; ++i) {
#pragma unroll
        for (int j = 0; j < 8; ++j) {
            const float v = zp[(size_t)(8 * i + j) << 12];
            float s = v * v;
            asm volatile("" : "+v"(s));
            a8[j] += s;
        }
    }
    const float szz = ((a8[0] + a8[1]) + (a8[2] + a8[3]))
                    + ((a8[4] + a8[5]) + (a8[6] + a8[7]));

    unsigned long long best = ~0ull;
    const unsigned cnt = rowcnt[r];
    if (cnt >= 1u && cnt <= (unsigned)CAND_CAP) {
        for (unsigned i = 0; i < cnt; ++i) {
            const int c = candrow[(size_t)r * CAND_CAP + i];
            const float* __restrict__ ec = emb + (c << 6);
            float acc = 0.0f;
#pragma unroll
            for (int k = 0; k < VQ_D; ++k)
                acc = __builtin_fmaf(zp[(size_t)k << 12], ec[k], acc);
            const float D = (szz - 2.0f * acc) + nE[c];
            const unsigned long long key = ((unsigned long long)fmono(D) << 32) | (unsigned)c;
            best = (key < best) ? key : best;
        }
    } else {  /* overflow or anomaly: validated full exact scan */
        for (int c = 0; c < VQ_N; ++c) {
            const float* __restrict__ ec = emb + (c << 6);
            float acc = 0.0f;
#pragma unroll
            for (int k = 0; k < VQ_D; ++k)
                acc = __builtin_fmaf(zp[(size_t)k << 12], ec[k], acc);
            const float D = (szz - 2.0f * acc) + nE[c];
            const unsigned long long key = ((unsigned long long)fmono(D) << 32) | (unsigned)c;
            best = (key < best) ? key : best;
        }
    }
    const int bc = (int)(best & 0xFFFFFFFFull);

    const float* __restrict__ eb = emb + (bc << 6);
    float lsum = 0.0f;
#pragma unroll
    for (int d = 0; d < VQ_D; ++d) {
        const float q = eb[d];
        const float zd = zp[(size_t)d << 12];
        out[((size_t)b << 18) + ((size_t)d << 12) + l] = q;
        const float df = q - zd;
        lsum = __builtin_fmaf(df, df, lsum);
    }
    out[VQ_ZQ + 1 + (size_t)r] = (float)bc;

#pragma unroll
    for (int off = 32; off > 0; off >>= 1)
        lsum += __shfl_down(lsum, off, 64);
    __shared__ float wsum[MAIN_BLOCK / 64];
    const int lane = threadIdx.x & 63;
    const int wid = threadIdx.x >> 6;
    if (lane == 0) wsum[wid] = lsum;
    __syncthreads();
    if (threadIdx.x == 0)
        partials[blockIdx.x] = (wsum[0] + wsum[1]) + (wsum[2] + wsum[3]);
}

__global__ void vq_final(const float* __restrict__ partials, float* __restrict__ out) {
    if (threadIdx.x == 0 && blockIdx.x == 0) {
        float s = 0.0f;
        for (int i = 0; i < MAIN_GRID; ++i) s += partials[i];
        const float mse = s / (float)VQ_ZQ;
        out[VQ_ZQ] = mse + 0.25f * mse;
    }
}

/* ================= fallback path (round-8, validated, ~335us) ========== */
__global__ void vq_norme_fb(const float* __restrict__ emb, float* __restrict__ nEf) {
    const int c = blockIdx.x * blockDim.x + threadIdx.x;
    if (c >= VQ_N) return;
    const float* ec = emb + (c << 6);
    f32x16 zvA, zvB, zvC, zvD;
#pragma unroll
    for (int d = 0; d < 16; ++d) {
        zvA[d] = ec[d]; zvB[d] = ec[d + 16]; zvC[d] = ec[d + 32]; zvD[d] = ec[d + 48];
    }
    float s;
    NP_PAIRWISE64_SQ(s);
    nEf[c] = s;
}
__global__ __launch_bounds__(256, 4) void vq_dist_fb(
    const float* __restrict__ z, const float* __restrict__ emb,
    const float* __restrict__ nEf, float2* __restrict__ cand) {
    __shared__ float zs[VQ_D * 64];
    const int w = threadIdx.x >> 6;
    const int lane = threadIdx.x & 63;
    const int r = blockIdx.x * 64 + lane;
    const int b = r >> 12;
    const int l = r & (VQ_L - 1);
    const float* zp = z + ((size_t)b << 18) + l;
#pragma unroll
    for (int j = 0; j < 16; ++j) {
        const int d = (w << 4) + j;
        zs[d * 64 + lane] = zp[(size_t)d << 12];
    }
    __syncthreads();
    float a8[8];
#pragma unroll
    for (int j = 0; j < 8; ++j) {
        const float v = zs[j * 64 + lane];
        float s = v * v; asm volatile("" : "+v"(s)); a8[j] = s;
    }
#pragma unroll
    for (int i = 1; i < 8; ++i) {
#pragma unroll
        for (int j = 0; j < 8; ++j) {
            const float v = zs[(8 * i + j) * 64 + lane];
            float s = v * v; asm volatile("" : "+v"(s)); a8[j] += s;
        }
    }
    const float szz = ((a8[0] + a8[1]) + (a8[2] + a8[3])) + ((a8[4] + a8[5]) + (a8[6] + a8[7]));
    const int c0 = __builtin_amdgcn_readfirstlane(w) * 256;
    float best = __builtin_inff();
    int bc = c0;
    for (int t = 0; t < 256; t += 16) {
        float acc[16];
#pragma unroll
        for (int j = 0; j < 16; ++j) acc[j] = 0.0f;
#pragma unroll
        for (int kk = 0; kk < VQ_D; kk += 4) {
            const float z0 = zs[(kk + 0) * 64 + lane];
            const float z1 = zs[(kk + 1) * 64 + lane];
            const float z2 = zs[(kk + 2) * 64 + lane];
            const float z3 = zs[(kk + 3) * 64 + lane];
#pragma unroll
            for (int j = 0; j < 16; ++j) {
                const float* __restrict__ ec = emb + ((c0 + t + j) << 6) + kk;
                acc[j] = __builtin_fmaf(z0, ec[0], acc[j]);
                acc[j] = __builtin_fmaf(z1, ec[1], acc[j]);
                acc[j] = __builtin_fmaf(z2, ec[2], acc[j]);
                acc[j] = __builtin_fmaf(z3, ec[3], acc[j]);
            }
        }
#pragma unroll
        for (int j = 0; j < 16; ++j) {
            const int c = c0 + t + j;
            const float dist = (szz - 2.0f * acc[j]) + nEf[c];
            if (dist < best) { best = dist; bc = c; }
        }
    }
    cand[(size_t)w * VQ_R + r] = make_float2(best, (float)bc);
}
__global__ __launch_bounds__(MAIN_BLOCK) void vq_epilogue_fb(
    const float* __restrict__ z, const float* __restrict__ emb,
    const float2* __restrict__ cand, float* __restrict__ out,
    float* __restrict__ partials) {
    const int r = blockIdx.x * MAIN_BLOCK + threadIdx.x;
    const int b = r >> 12;
    const int l = r & (VQ_L - 1);
    float best = __builtin_inff();
    int bc = 0;
#pragma unroll
    for (int seg = 0; seg < 4; ++seg) {
        const float2 cd = cand[(size_t)seg * VQ_R + r];
        if (cd.x < best) { best = cd.x; bc = (int)cd.y; }
    }
    const float* zp = z + ((size_t)b << 18) + l;
    const float* __restrict__ eb = emb + (bc << 6);
    float lsum = 0.0f;
#pragma unroll
    for (int d = 0; d < VQ_D; ++d) {
        const float q = eb[d];
        const float zd = zp[(size_t)d << 12];
        out[((size_t)b << 18) + ((size_t)d << 12) + l] = q;
        const float df = q - zd;
        lsum = __builtin_fmaf(df, df, lsum);
    }
    out[VQ_ZQ + 1 + (size_t)r] = (float)bc;
#pragma unroll
    for (int off = 32; off > 0; off >>= 1)
        lsum += __shfl_down(lsum, off, 64);
    __shared__ float wsum[MAIN_BLOCK / 64];
    const int lane = threadIdx.x & 63;
    const int wid = threadIdx.x >> 6;
    if (lane == 0) wsum[wid] = lsum;
    __syncthreads();
    if (threadIdx.x == 0)
        partials[blockIdx.x] = (wsum[0] + wsum[1]) + (wsum[2] + wsum[3]);
}

/* ================= launch ================= */
extern "C" void kernel_launch(void* const* d_in, const int* in_sizes, int n_in,
                              void* d_out, int out_size, void* d_ws, size_t ws_size,
                              hipStream_t stream) {
    const float* z   = (const float*)d_in[0];
    const float* emb = (const float*)d_in[1];
    float* out = (float*)d_out;
    char* ws = (char*)d_ws;

    /* layout (16B-aligned) */
    unsigned short* z_bf   = (unsigned short*)(ws);                       /* 16777216 B */
    unsigned short* emb_bf = (unsigned short*)(ws + 16777216);            /*   131072 B */
    unsigned short* candrw = (unsigned short*)(ws + 16908288);            /*  4194304 B */
    float*          mrg    = (float*)(ws + 21102592);                     /*   524288 B */
    unsigned*       rowcnt = (unsigned*)(ws + 21626880);                  /*   524288 B */
    float*          nE     = (float*)(ws + 22151168);                     /*     4096 B */
    float*          parts  = (float*)(ws + 22155264);                     /*     2048 B */
    unsigned*       nEmax  = (unsigned*)(ws + 22157312);                  /*        4 B */
    const size_t need = 22157376;

    if (ws_size >= need) {
        vq_init<<<dim3(512), dim3(256), 0, stream>>>(rowcnt, nEmax);
        vq_prep_emb<<<dim3(4), dim3(256), 0, stream>>>(emb, nE, emb_bf, nEmax);
        vq_prep_z<<<dim3(512), dim3(256), 0, stream>>>(z, nEmax, z_bf, mrg);
        vq_screen<<<dim3(VQ_R / 256, NSEG), dim3(256), 0, stream>>>(
            z_bf, emb_bf, nE, mrg, rowcnt, candrw);
        vq_exact<<<dim3(MAIN_GRID), dim3(MAIN_BLOCK), 0, stream>>>(z, emb, nE, rowcnt,
                                                                   candrw, out, parts);
        vq_final<<<dim3(1), dim3(64), 0, stream>>>(parts, out);
    } else {
        /* validated round-8 fallback (~4.2 MB ws) */
        float* nEf = (float*)ws;
        float* partials = nEf + VQ_N;
        float2* cand = (float2*)(partials + MAIN_GRID);
        vq_norme_fb<<<dim3(4), dim3(256), 0, stream>>>(emb, nEf);
        vq_dist_fb<<<dim3(VQ_R / 64), dim3(256), 0, stream>>>(z, emb, nEf, cand);
        vq_epilogue_fb<<<dim3(MAIN_GRID), dim3(MAIN_BLOCK), 0, stream>>>(z, emb, cand, out, partials);
        vq_final<<<dim3(1), dim3(64), 0, stream>>>(partials, out);
    }
}

// Round 16
// 324.182 us; speedup vs baseline: 1.8305x; 1.8305x over previous
//
#include <hip/hip_runtime.h>

#define VQ_B 32
#define VQ_D 64
#define VQ_L 4096
#define VQ_N 1024
#define VQ_R (VQ_B * VQ_L)            /* 131072 rows */
#define VQ_ZQ ((size_t)VQ_R * VQ_D)   /* 8388608 z_q elements */
#define MAIN_BLOCK 256
#define MAIN_GRID (VQ_R / MAIN_BLOCK) /* 512 */
#define CAND_CAP 16
#define EPSREL 2.0e-3f                /* > 2^-9 = 1.95e-3 RNE bf16 unit roundoff */
#define MRG_ABS 1e-4f                 /* reorder + quant + fp32-accum slack */
#define RT 4                          /* row-tiles per wave (64 rows) */
#define NSEG 4                        /* code segments (grid.y) */
#define SEGC (VQ_N / NSEG)            /* 256 codes per segment */
#define NCT (SEGC / 16)               /* 16 code-tiles per segment */
#define KEYQ 0xFFFFFC00u              /* g-key quantization mask (10 code bits) */

typedef __attribute__((ext_vector_type(16))) float f32x16;
typedef __attribute__((ext_vector_type(8)))  short short8;   /* 8 bf16 */
typedef __attribute__((ext_vector_type(4)))  float f32x4;
typedef __attribute__((ext_vector_type(4)))  unsigned int u32x4;

/* ---------- monotone float<->u32 keys ---------- */
__device__ __forceinline__ unsigned fmono(float x) {
    unsigned u = __builtin_bit_cast(unsigned, x);
    return (u & 0x80000000u) ? ~u : (u | 0x80000000u);
}
__device__ __forceinline__ float fmono_dec(unsigned k) {
    unsigned u = (k & 0x80000000u) ? (k & 0x7FFFFFFFu) : ~k;
    return __builtin_bit_cast(float, u);
}
__device__ __forceinline__ unsigned short f2bf(float x) {
    __bf16 h = (__bf16)x;  /* RNE */
    return __builtin_bit_cast(unsigned short, h);
}

/* ---------- validated numpy-pairwise norm machinery ---------- */
#define ZVE(i) ((i) < 16 ? zvA[(i) & 15] : (i) < 32 ? zvB[(i) & 15] \
               : (i) < 48 ? zvC[(i) & 15] : zvD[(i) & 15])
#define SQB(x) ({ float s_ = (x) * (x); asm volatile("" : "+v"(s_)); s_; })
#define NP_PAIRWISE64_SQ(dst)                                                  \
    do {                                                                       \
        float r0 = SQB(ZVE(0)), r1 = SQB(ZVE(1)), r2 = SQB(ZVE(2)),            \
              r3 = SQB(ZVE(3)), r4 = SQB(ZVE(4)), r5 = SQB(ZVE(5)),            \
              r6 = SQB(ZVE(6)), r7 = SQB(ZVE(7));                              \
        _Pragma("unroll")                                                      \
        for (int i_ = 1; i_ < 8; ++i_) {                                       \
            r0 += SQB(ZVE(8 * i_ + 0)); r1 += SQB(ZVE(8 * i_ + 1));            \
            r2 += SQB(ZVE(8 * i_ + 2)); r3 += SQB(ZVE(8 * i_ + 3));            \
            r4 += SQB(ZVE(8 * i_ + 4)); r5 += SQB(ZVE(8 * i_ + 5));            \
            r6 += SQB(ZVE(8 * i_ + 6)); r7 += SQB(ZVE(8 * i_ + 7));            \
        }                                                                      \
        dst = ((r0 + r1) + (r2 + r3)) + ((r4 + r5) + (r6 + r7));               \
    } while (0)

/* ---------- init: rowcnt=0, nEmax=0 ---------- */
__global__ void vq_init(unsigned* __restrict__ rowcnt, unsigned* __restrict__ nEmax) {
    const int i = blockIdx.x * blockDim.x + threadIdx.x;
    if (i < VQ_R) rowcnt[i] = 0u;
    if (i == 0) *nEmax = 0u;
}

/* ---------- prep emb: exact nE (np chain), emb->bf16, nEmax ---------- */
__global__ void vq_prep_emb(const float* __restrict__ emb, float* __restrict__ nE,
                            unsigned short* __restrict__ emb_bf,
                            unsigned* __restrict__ nEmax) {
    const int c = blockIdx.x * blockDim.x + threadIdx.x;
    if (c >= VQ_N) return;
    const float* ec = emb + (c << 6);
    f32x16 zvA, zvB, zvC, zvD;
#pragma unroll
    for (int d = 0; d < 16; ++d) {
        zvA[d] = ec[d];
        zvB[d] = ec[d + 16];
        zvC[d] = ec[d + 32];
        zvD[d] = ec[d + 48];
    }
    float s;
    NP_PAIRWISE64_SQ(s);
    nE[c] = s;
    atomicMax(nEmax, fmono(s));
#pragma unroll
    for (int d = 0; d < 64; ++d) emb_bf[(c << 6) + d] = f2bf(ec[d]);
}

/* ---------- prep z: bf16 rows + per-row margin ----------
   mrg = 2E + slack, E = 4u*||z||*||e||max, u = 2^-9 (RNE). */
__global__ __launch_bounds__(256) void vq_prep_z(
    const float* __restrict__ z, const unsigned* __restrict__ nEmax,
    unsigned short* __restrict__ z_bf, float* __restrict__ mrg) {
    const int r = blockIdx.x * 256 + threadIdx.x;
    const int b = r >> 12;
    const int l = r & (VQ_L - 1);
    const float* zp = z + ((size_t)b << 18) + l;
    unsigned short* o = z_bf + ((size_t)r << 6);
    float s = 0.0f;
#pragma unroll
    for (int j8 = 0; j8 < 8; ++j8) {
        unsigned w[4];
#pragma unroll
        for (int p = 0; p < 4; ++p) {
            const float v0 = zp[(size_t)(j8 * 8 + 2 * p) << 12];
            const float v1 = zp[(size_t)(j8 * 8 + 2 * p + 1) << 12];
            s = __builtin_fmaf(v0, v0, s);
            s = __builtin_fmaf(v1, v1, s);
            w[p] = (unsigned)f2bf(v0) | ((unsigned)f2bf(v1) << 16);
        }
        *(u32x4*)(o + j8 * 8) = (u32x4){w[0], w[1], w[2], w[3]};
    }
    const float nem = fmono_dec(*nEmax);
    mrg[r] = 8.0f * EPSREL * sqrtf(s * nem) + MRG_ABS;
}

/* ---------- single-pass MFMA screen (round-15 structure, validated) ----
   Emission packs the quantized g-key with the code: (fmono(g)&KEYQ)|c.
   This lets vq_exact prune candidates to the global-margin set (~1.2/row)
   before doing exact dots — fixing round-15's serial-tail regression. */
__global__ __launch_bounds__(256, 4) void vq_screen(
    const unsigned short* __restrict__ z_bf, const unsigned short* __restrict__ emb_bf,
    const float* __restrict__ nE, const float* __restrict__ mrg,
    unsigned* __restrict__ rowcnt, unsigned* __restrict__ candrow) {
    __shared__ unsigned short ebS[8 * SEGC * 8];  /* 32 KB, chunk-major */
    __shared__ float neS[SEGC];                   /* 1 KB */
    const int tid = threadIdx.x;
    const int c0 = blockIdx.y * SEGC;             /* block-uniform -> scalar */

    for (int q = tid; q < SEGC * 8; q += 256) {
        const short8 v = *(const short8*)(emb_bf + ((size_t)c0 << 6) + q * 8);
        *(short8*)(ebS + ((q & 7) * SEGC + (q >> 3)) * 8) = v;
    }
    neS[tid] = nE[c0 + tid];
    __syncthreads();

    const int w = tid >> 6, lane = tid & 63;
    const int cl = lane & 15, grp = lane >> 4;
    const int rowbase = blockIdx.x * 256 + w * (16 * RT);

    short8 a0[RT], a1[RT];
#pragma unroll
    for (int t = 0; t < RT; ++t) {
        const unsigned short* za = z_bf + ((size_t)(rowbase + t * 16 + cl) << 6) + grp * 8;
        a0[t] = *(const short8*)(za);
        a1[t] = *(const short8*)(za + 32);
    }

    int row_r[RT][4];
#pragma unroll
    for (int t = 0; t < RT; ++t)
#pragma unroll
        for (int reg = 0; reg < 4; ++reg)
            row_r[t][reg] = rowbase + t * 16 + grp * 4 + reg;

    float mt[RT][4];
#pragma unroll
    for (int t = 0; t < RT; ++t)
#pragma unroll
        for (int reg = 0; reg < 4; ++reg) mt[t][reg] = __builtin_inff();

    /* ---- sweep A: per-row min over this segment's codes ---- */
#pragma unroll 2
    for (int ct = 0; ct < NCT; ++ct) {
        const int cr = ct * 16 + cl;
        const short8 b0 = *(const short8*)(ebS + (grp * SEGC + cr) * 8);
        const short8 b1 = *(const short8*)(ebS + ((grp + 4) * SEGC + cr) * 8);
        const float ne = neS[cr];
        f32x4 acc[RT];
#pragma unroll
        for (int t = 0; t < RT; ++t) {
            acc[t] = (f32x4){0.0f, 0.0f, 0.0f, 0.0f};
            acc[t] = __builtin_amdgcn_mfma_f32_16x16x32_bf16(a0[t], b0, acc[t], 0, 0, 0);
            acc[t] = __builtin_amdgcn_mfma_f32_16x16x32_bf16(a1[t], b1, acc[t], 0, 0, 0);
        }
#pragma unroll
        for (int t = 0; t < RT; ++t)
#pragma unroll
            for (int reg = 0; reg < 4; ++reg) {
                const float g = __builtin_fmaf(-2.0f, acc[t][reg], ne);
                mt[t][reg] = fminf(mt[t][reg], g);
            }
    }

    /* ---- allreduce across cl lanes, thr = min + mrg (in-place) ---- */
#pragma unroll
    for (int t = 0; t < RT; ++t)
#pragma unroll
        for (int reg = 0; reg < 4; ++reg) {
            float v = mt[t][reg];
            v = fminf(v, __shfl_xor(v, 1));
            v = fminf(v, __shfl_xor(v, 2));
            v = fminf(v, __shfl_xor(v, 4));
            v = fminf(v, __shfl_xor(v, 8));
            mt[t][reg] = v + mrg[row_r[t][reg]];
        }

    /* ---- sweep B: identical g~ bits; emit packed (g-key | code) ---- */
#pragma unroll 2
    for (int ct = 0; ct < NCT; ++ct) {
        const int cr = ct * 16 + cl;
        const short8 b0 = *(const short8*)(ebS + (grp * SEGC + cr) * 8);
        const short8 b1 = *(const short8*)(ebS + ((grp + 4) * SEGC + cr) * 8);
        const float ne = neS[cr];
        f32x4 acc[RT];
#pragma unroll
        for (int t = 0; t < RT; ++t) {
            acc[t] = (f32x4){0.0f, 0.0f, 0.0f, 0.0f};
            acc[t] = __builtin_amdgcn_mfma_f32_16x16x32_bf16(a0[t], b0, acc[t], 0, 0, 0);
            acc[t] = __builtin_amdgcn_mfma_f32_16x16x32_bf16(a1[t], b1, acc[t], 0, 0, 0);
        }
#pragma unroll
        for (int t = 0; t < RT; ++t)
#pragma unroll
            for (int reg = 0; reg < 4; ++reg) {
                const float g = __builtin_fmaf(-2.0f, acc[t][reg], ne);
                if (g <= mt[t][reg]) {
                    const unsigned idx = atomicAdd(&rowcnt[row_r[t][reg]], 1u);
                    if (idx < CAND_CAP)
                        candrow[(size_t)row_r[t][reg] * CAND_CAP + idx] =
                            (fmono(g) & KEYQ) | (unsigned)(c0 + cr);
                }
            }
    }
}

/* ---------- exact phase: prune by g-key, exact D on survivors ---------- */
__global__ __launch_bounds__(MAIN_BLOCK) void vq_exact(
    const float* __restrict__ z, const float* __restrict__ emb,
    const float* __restrict__ nE, const float* __restrict__ mrg,
    const unsigned* __restrict__ rowcnt, const unsigned* __restrict__ candrow,
    float* __restrict__ out, float* __restrict__ partials) {
    const int r = blockIdx.x * MAIN_BLOCK + threadIdx.x;
    const int b = r >> 12;
    const int l = r & (VQ_L - 1);
    const float* zp = z + ((size_t)b << 18) + l;

    /* szz: numpy pairwise (8 accs, d=8i+j ascending, squares pre-rounded) */
    float a8[8];
#pragma unroll
    for (int j = 0; j < 8; ++j) {
        const float v = zp[(size_t)j << 12];
        float s = v * v;
        asm volatile("" : "+v"(s));
        a8[j] = s;
    }
#pragma unroll
    for (int i = 1; i < 8; ++i) {
#pragma unroll
        for (int j = 0; j < 8; ++j) {
            const float v = zp[(size_t)(8 * i + j) << 12];
            float s = v * v;
            asm volatile("" : "+v"(s));
            a8[j] += s;
        }
    }
    const float szz = ((a8[0] + a8[1]) + (a8[2] + a8[3]))
                    + ((a8[4] + a8[5]) + (a8[6] + a8[7]));

    unsigned long long best = ~0ull;
    const unsigned cnt = rowcnt[r];
    if (cnt >= 1u && cnt <= (unsigned)CAND_CAP) {
        /* pass 1: min quantized g-key over candidate set */
        unsigned kmin = 0xFFFFFFFFu;
        for (unsigned i = 0; i < cnt; ++i) {
            const unsigned key = candrow[(size_t)r * CAND_CAP + i];
            kmin = (key < kmin) ? key : kmin;
        }
        /* prune threshold: decoded min + mrg (covers 2E + quant + slack) */
        const float gthr = fmono_dec(kmin & KEYQ) + mrg[r];
        /* pass 2: exact D only for pruned survivors (~1.2/row) */
        for (unsigned i = 0; i < cnt; ++i) {
            const unsigned key = candrow[(size_t)r * CAND_CAP + i];
            if (fmono_dec(key & KEYQ) > gthr) continue;
            const int c = (int)(key & 1023u);
            const float* __restrict__ ec = emb + (c << 6);
            float acc = 0.0f;
#pragma unroll
            for (int k = 0; k < VQ_D; ++k)
                acc = __builtin_fmaf(zp[(size_t)k << 12], ec[k], acc);
            const float D = (szz - 2.0f * acc) + nE[c];
            const unsigned long long bk = ((unsigned long long)fmono(D) << 32) | (unsigned)c;
            best = (bk < best) ? bk : best;
        }
    } else {  /* overflow or anomaly: validated full exact scan */
        for (int c = 0; c < VQ_N; ++c) {
            const float* __restrict__ ec = emb + (c << 6);
            float acc = 0.0f;
#pragma unroll
            for (int k = 0; k < VQ_D; ++k)
                acc = __builtin_fmaf(zp[(size_t)k << 12], ec[k], acc);
            const float D = (szz - 2.0f * acc) + nE[c];
            const unsigned long long bk = ((unsigned long long)fmono(D) << 32) | (unsigned)c;
            best = (bk < best) ? bk : best;
        }
    }
    const int bc = (int)(best & 1023u);

    const float* __restrict__ eb = emb + (bc << 6);
    float lsum = 0.0f;
#pragma unroll
    for (int d = 0; d < VQ_D; ++d) {
        const float q = eb[d];
        const float zd = zp[(size_t)d << 12];
        out[((size_t)b << 18) + ((size_t)d << 12) + l] = q;
        const float df = q - zd;
        lsum = __builtin_fmaf(df, df, lsum);
    }
    out[VQ_ZQ + 1 + (size_t)r] = (float)bc;

#pragma unroll
    for (int off = 32; off > 0; off >>= 1)
        lsum += __shfl_down(lsum, off, 64);
    __shared__ float wsum[MAIN_BLOCK / 64];
    const int lane = threadIdx.x & 63;
    const int wid = threadIdx.x >> 6;
    if (lane == 0) wsum[wid] = lsum;
    __syncthreads();
    if (threadIdx.x == 0)
        partials[blockIdx.x] = (wsum[0] + wsum[1]) + (wsum[2] + wsum[3]);
}

__global__ void vq_final(const float* __restrict__ partials, float* __restrict__ out) {
    if (threadIdx.x == 0 && blockIdx.x == 0) {
        float s = 0.0f;
        for (int i = 0; i < MAIN_GRID; ++i) s += partials[i];
        const float mse = s / (float)VQ_ZQ;
        out[VQ_ZQ] = mse + 0.25f * mse;
    }
}

/* ================= fallback path (round-8, validated, ~335us) ========== */
__global__ void vq_norme_fb(const float* __restrict__ emb, float* __restrict__ nEf) {
    const int c = blockIdx.x * blockDim.x + threadIdx.x;
    if (c >= VQ_N) return;
    const float* ec = emb + (c << 6);
    f32x16 zvA, zvB, zvC, zvD;
#pragma unroll
    for (int d = 0; d < 16; ++d) {
        zvA[d] = ec[d]; zvB[d] = ec[d + 16]; zvC[d] = ec[d + 32]; zvD[d] = ec[d + 48];
    }
    float s;
    NP_PAIRWISE64_SQ(s);
    nEf[c] = s;
}
__global__ __launch_bounds__(256, 4) void vq_dist_fb(
    const float* __restrict__ z, const float* __restrict__ emb,
    const float* __restrict__ nEf, float2* __restrict__ cand) {
    __shared__ float zs[VQ_D * 64];
    const int w = threadIdx.x >> 6;
    const int lane = threadIdx.x & 63;
    const int r = blockIdx.x * 64 + lane;
    const int b = r >> 12;
    const int l = r & (VQ_L - 1);
    const float* zp = z + ((size_t)b << 18) + l;
#pragma unroll
    for (int j = 0; j < 16; ++j) {
        const int d = (w << 4) + j;
        zs[d * 64 + lane] = zp[(size_t)d << 12];
    }
    __syncthreads();
    float a8[8];
#pragma unroll
    for (int j = 0; j < 8; ++j) {
        const float v = zs[j * 64 + lane];
        float s = v * v; asm volatile("" : "+v"(s)); a8[j] = s;
    }
#pragma unroll
    for (int i = 1; i < 8; ++i) {
#pragma unroll
        for (int j = 0; j < 8; ++j) {
            const float v = zs[(8 * i + j) * 64 + lane];
            float s = v * v; asm volatile("" : "+v"(s)); a8[j] += s;
        }
    }
    const float szz = ((a8[0] + a8[1]) + (a8[2] + a8[3])) + ((a8[4] + a8[5]) + (a8[6] + a8[7]));
    const int c0 = __builtin_amdgcn_readfirstlane(w) * 256;
    float best = __builtin_inff();
    int bc = c0;
    for (int t = 0; t < 256; t += 16) {
        float acc[16];
#pragma unroll
        for (int j = 0; j < 16; ++j) acc[j] = 0.0f;
#pragma unroll
        for (int kk = 0; kk < VQ_D; kk += 4) {
            const float z0 = zs[(kk + 0) * 64 + lane];
            const float z1 = zs[(kk + 1) * 64 + lane];
            const float z2 = zs[(kk + 2) * 64 + lane];
            const float z3 = zs[(kk + 3) * 64 + lane];
#pragma unroll
            for (int j = 0; j < 16; ++j) {
                const float* __restrict__ ec = emb + ((c0 + t + j) << 6) + kk;
                acc[j] = __builtin_fmaf(z0, ec[0], acc[j]);
                acc[j] = __builtin_fmaf(z1, ec[1], acc[j]);
                acc[j] = __builtin_fmaf(z2, ec[2], acc[j]);
                acc[j] = __builtin_fmaf(z3, ec[3], acc[j]);
            }
        }
#pragma unroll
        for (int j = 0; j < 16; ++j) {
            const int c = c0 + t + j;
            const float dist = (szz - 2.0f * acc[j]) + nEf[c];
            if (dist < best) { best = dist; bc = c; }
        }
    }
    cand[(size_t)w * VQ_R + r] = make_float2(best, (float)bc);
}
__global__ __launch_bounds__(MAIN_BLOCK) void vq_epilogue_fb(
    const float* __restrict__ z, const float* __restrict__ emb,
    const float2* __restrict__ cand, float* __restrict__ out,
    float* __restrict__ partials) {
    const int r = blockIdx.x * MAIN_BLOCK + threadIdx.x;
    const int b = r >> 12;
    const int l = r & (VQ_L - 1);
    float best = __builtin_inff();
    int bc = 0;
#pragma unroll
    for (int seg = 0; seg < 4; ++seg) {
        const float2 cd = cand[(size_t)seg * VQ_R + r];
        if (cd.x < best) { best = cd.x; bc = (int)cd.y; }
    }
    const float* zp = z + ((size_t)b << 18) + l;
    const float* __restrict__ eb = emb + (bc << 6);
    float lsum = 0.0f;
#pragma unroll
    for (int d = 0; d < VQ_D; ++d) {
        const float q = eb[d];
        const float zd = zp[(size_t)d << 12];
        out[((size_t)b << 18) + ((size_t)d << 12) + l] = q;
        const float df = q - zd;
        lsum = __builtin_fmaf(df, df, lsum);
    }
    out[VQ_ZQ + 1 + (size_t)r] = (float)bc;
#pragma unroll
    for (int off = 32; off > 0; off >>= 1)
        lsum += __shfl_down(lsum, off, 64);
    __shared__ float wsum[MAIN_BLOCK / 64];
    const int lane = threadIdx.x & 63;
    const int wid = threadIdx.x >> 6;
    if (lane == 0) wsum[wid] = lsum;
    __syncthreads();
    if (threadIdx.x == 0)
        partials[blockIdx.x] = (wsum[0] + wsum[1]) + (wsum[2] + wsum[3]);
}

/* ================= launch ================= */
extern "C" void kernel_launch(void* const* d_in, const int* in_sizes, int n_in,
                              void* d_out, int out_size, void* d_ws, size_t ws_size,
                              hipStream_t stream) {
    const float* z   = (const float*)d_in[0];
    const float* emb = (const float*)d_in[1];
    float* out = (float*)d_out;
    char* ws = (char*)d_ws;

    /* layout (16B-aligned) */
    unsigned short* z_bf   = (unsigned short*)(ws);                       /* 16777216 B */
    unsigned short* emb_bf = (unsigned short*)(ws + 16777216);            /*   131072 B */
    unsigned*       candrw = (unsigned*)(ws + 16908288);                  /*  8388608 B */
    float*          mrg    = (float*)(ws + 25296896);                     /*   524288 B */
    unsigned*       rowcnt = (unsigned*)(ws + 25821184);                  /*   524288 B */
    float*          nE     = (float*)(ws + 26345472);                     /*     4096 B */
    float*          parts  = (float*)(ws + 26349568);                     /*     2048 B */
    unsigned*       nEmax  = (unsigned*)(ws + 26351616);                  /*        4 B */
    const size_t need = 26351680;

    if (ws_size >= need) {
        vq_init<<<dim3(512), dim3(256), 0, stream>>>(rowcnt, nEmax);
        vq_prep_emb<<<dim3(4), dim3(256), 0, stream>>>(emb, nE, emb_bf, nEmax);
        vq_prep_z<<<dim3(512), dim3(256), 0, stream>>>(z, nEmax, z_bf, mrg);
        vq_screen<<<dim3(VQ_R / 256, NSEG), dim3(256), 0, stream>>>(
            z_bf, emb_bf, nE, mrg, rowcnt, candrw);
        vq_exact<<<dim3(MAIN_GRID), dim3(MAIN_BLOCK), 0, stream>>>(z, emb, nE, mrg,
                                                                   rowcnt, candrw, out, parts);
        vq_final<<<dim3(1), dim3(64), 0, stream>>>(parts, out);
    } else {
        /* validated round-8 fallback (~4.2 MB ws) */
        float* nEf = (float*)ws;
        float* partials = nEf + VQ_N;
        float2* cand = (float2*)(partials + MAIN_GRID);
        vq_norme_fb<<<dim3(4), dim3(256), 0, stream>>>(emb, nEf);
        vq_dist_fb<<<dim3(VQ_R / 64), dim3(256), 0, stream>>>(z, emb, nEf, cand);
        vq_epilogue_fb<<<dim3(MAIN_GRID), dim3(MAIN_BLOCK), 0, stream>>>(z, emb, cand, out, partials);
        vq_final<<<dim3(1), dim3(64), 0, stream>>>(partials, out);
    }
}

// Round 17
// 193.932 us; speedup vs baseline: 3.0600x; 1.6716x over previous
//
#include <hip/hip_runtime.h>

#define VQ_B 32
#define VQ_D 64
#define VQ_L 4096
#define VQ_N 1024
#define VQ_R (VQ_B * VQ_L)            /* 131072 rows */
#define VQ_ZQ ((size_t)VQ_R * VQ_D)   /* 8388608 z_q elements */
#define MAIN_BLOCK 256
#define MAIN_GRID (VQ_R / MAIN_BLOCK) /* 512 */
#define CAND_CAP 16
#define EPSREL 2.0e-3f                /* > 2^-9 RNE bf16 unit roundoff */
#define MRG_ABS 1e-4f                 /* reorder + quant + fp32-accum slack */
#define RT 4                          /* row-tiles per wave (64 rows) */
#define NSEG 4                        /* code segments (grid.y) */
#define SEGC (VQ_N / NSEG)            /* 256 codes per segment */
#define NCT (SEGC / 16)               /* 16 code-tiles per segment */
#define KEYQ 0xFFFFFC00u              /* g-key quantization mask (10 code bits) */
#define OV_WAVES 1024                 /* overflow kernel: 256 blk x 4 waves */

typedef __attribute__((ext_vector_type(16))) float f32x16;
typedef __attribute__((ext_vector_type(8)))  short short8;   /* 8 bf16 */
typedef __attribute__((ext_vector_type(4)))  float f32x4;
typedef __attribute__((ext_vector_type(4)))  unsigned int u32x4;

/* ---------- monotone float<->u32 keys ---------- */
__device__ __forceinline__ unsigned fmono(float x) {
    unsigned u = __builtin_bit_cast(unsigned, x);
    return (u & 0x80000000u) ? ~u : (u | 0x80000000u);
}
__device__ __forceinline__ float fmono_dec(unsigned k) {
    unsigned u = (k & 0x80000000u) ? (k & 0x7FFFFFFFu) : ~k;
    return __builtin_bit_cast(float, u);
}
__device__ __forceinline__ unsigned short f2bf(float x) {
    __bf16 h = (__bf16)x;  /* RNE */
    return __builtin_bit_cast(unsigned short, h);
}

/* ---------- validated numpy-pairwise norm machinery ---------- */
#define ZVE(i) ((i) < 16 ? zvA[(i) & 15] : (i) < 32 ? zvB[(i) & 15] \
               : (i) < 48 ? zvC[(i) & 15] : zvD[(i) & 15])
#define SQB(x) ({ float s_ = (x) * (x); asm volatile("" : "+v"(s_)); s_; })
#define NP_PAIRWISE64_SQ(dst)                                                  \
    do {                                                                       \
        float r0 = SQB(ZVE(0)), r1 = SQB(ZVE(1)), r2 = SQB(ZVE(2)),            \
              r3 = SQB(ZVE(3)), r4 = SQB(ZVE(4)), r5 = SQB(ZVE(5)),            \
              r6 = SQB(ZVE(6)), r7 = SQB(ZVE(7));                              \
        _Pragma("unroll")                                                      \
        for (int i_ = 1; i_ < 8; ++i_) {                                       \
            r0 += SQB(ZVE(8 * i_ + 0)); r1 += SQB(ZVE(8 * i_ + 1));            \
            r2 += SQB(ZVE(8 * i_ + 2)); r3 += SQB(ZVE(8 * i_ + 3));            \
            r4 += SQB(ZVE(8 * i_ + 4)); r5 += SQB(ZVE(8 * i_ + 5));            \
            r6 += SQB(ZVE(8 * i_ + 6)); r7 += SQB(ZVE(8 * i_ + 7));            \
        }                                                                      \
        dst = ((r0 + r1) + (r2 + r3)) + ((r4 + r5) + (r6 + r7));               \
    } while (0)

/* szz for one row from strided z (numpy 8-acc order, squares pre-rounded) */
#define NP_SZZ_FROM_ZP(szz_out)                                                \
    do {                                                                       \
        float a8_[8];                                                          \
        _Pragma("unroll")                                                      \
        for (int j_ = 0; j_ < 8; ++j_) {                                       \
            const float v_ = zp[(size_t)j_ << 12];                             \
            float s_ = v_ * v_;                                                \
            asm volatile("" : "+v"(s_));                                       \
            a8_[j_] = s_;                                                      \
        }                                                                      \
        _Pragma("unroll")                                                      \
        for (int i_ = 1; i_ < 8; ++i_) {                                       \
            _Pragma("unroll")                                                  \
            for (int j_ = 0; j_ < 8; ++j_) {                                   \
                const float v_ = zp[(size_t)(8 * i_ + j_) << 12];              \
                float s_ = v_ * v_;                                            \
                asm volatile("" : "+v"(s_));                                   \
                a8_[j_] += s_;                                                 \
            }                                                                  \
        }                                                                      \
        szz_out = ((a8_[0] + a8_[1]) + (a8_[2] + a8_[3]))                      \
                + ((a8_[4] + a8_[5]) + (a8_[6] + a8_[7]));                     \
    } while (0)

/* ---------- init: rowcnt=0, nEmax=0, ovcnt=0, ovloss=0 ---------- */
__global__ void vq_init(unsigned* __restrict__ rowcnt, unsigned* __restrict__ nEmax,
                        unsigned* __restrict__ ovcnt, float* __restrict__ ovloss) {
    const int i = blockIdx.x * blockDim.x + threadIdx.x;
    if (i < VQ_R) rowcnt[i] = 0u;
    if (i == 0) { *nEmax = 0u; *ovcnt = 0u; *ovloss = 0.0f; }
}

/* ---------- prep emb: exact nE (np chain), emb->bf16, nEmax ---------- */
__global__ void vq_prep_emb(const float* __restrict__ emb, float* __restrict__ nE,
                            unsigned short* __restrict__ emb_bf,
                            unsigned* __restrict__ nEmax) {
    const int c = blockIdx.x * blockDim.x + threadIdx.x;
    if (c >= VQ_N) return;
    const float* ec = emb + (c << 6);
    f32x16 zvA, zvB, zvC, zvD;
#pragma unroll
    for (int d = 0; d < 16; ++d) {
        zvA[d] = ec[d];
        zvB[d] = ec[d + 16];
        zvC[d] = ec[d + 32];
        zvD[d] = ec[d + 48];
    }
    float s;
    NP_PAIRWISE64_SQ(s);
    nE[c] = s;
    atomicMax(nEmax, fmono(s));
#pragma unroll
    for (int d = 0; d < 64; ++d) emb_bf[(c << 6) + d] = f2bf(ec[d]);
}

/* ---------- prep z: bf16 rows + per-row margin ---------- */
__global__ __launch_bounds__(256) void vq_prep_z(
    const float* __restrict__ z, const unsigned* __restrict__ nEmax,
    unsigned short* __restrict__ z_bf, float* __restrict__ mrg) {
    const int r = blockIdx.x * 256 + threadIdx.x;
    const int b = r >> 12;
    const int l = r & (VQ_L - 1);
    const float* zp = z + ((size_t)b << 18) + l;
    unsigned short* o = z_bf + ((size_t)r << 6);
    float s = 0.0f;
#pragma unroll
    for (int j8 = 0; j8 < 8; ++j8) {
        unsigned w[4];
#pragma unroll
        for (int p = 0; p < 4; ++p) {
            const float v0 = zp[(size_t)(j8 * 8 + 2 * p) << 12];
            const float v1 = zp[(size_t)(j8 * 8 + 2 * p + 1) << 12];
            s = __builtin_fmaf(v0, v0, s);
            s = __builtin_fmaf(v1, v1, s);
            w[p] = (unsigned)f2bf(v0) | ((unsigned)f2bf(v1) << 16);
        }
        *(u32x4*)(o + j8 * 8) = (u32x4){w[0], w[1], w[2], w[3]};
    }
    const float nem = fmono_dec(*nEmax);
    mrg[r] = 8.0f * EPSREL * sqrtf(s * nem) + MRG_ABS;
}

/* ---------- single-pass MFMA screen (validated R15/R16 structure) ---------- */
__global__ __launch_bounds__(256, 4) void vq_screen(
    const unsigned short* __restrict__ z_bf, const unsigned short* __restrict__ emb_bf,
    const float* __restrict__ nE, const float* __restrict__ mrg,
    unsigned* __restrict__ rowcnt, unsigned* __restrict__ candrow) {
    __shared__ unsigned short ebS[8 * SEGC * 8];  /* 32 KB, chunk-major */
    __shared__ float neS[SEGC];                   /* 1 KB */
    const int tid = threadIdx.x;
    const int c0 = blockIdx.y * SEGC;             /* block-uniform -> scalar */

    for (int q = tid; q < SEGC * 8; q += 256) {
        const short8 v = *(const short8*)(emb_bf + ((size_t)c0 << 6) + q * 8);
        *(short8*)(ebS + ((q & 7) * SEGC + (q >> 3)) * 8) = v;
    }
    neS[tid] = nE[c0 + tid];
    __syncthreads();

    const int w = tid >> 6, lane = tid & 63;
    const int cl = lane & 15, grp = lane >> 4;
    const int rowbase = blockIdx.x * 256 + w * (16 * RT);

    short8 a0[RT], a1[RT];
#pragma unroll
    for (int t = 0; t < RT; ++t) {
        const unsigned short* za = z_bf + ((size_t)(rowbase + t * 16 + cl) << 6) + grp * 8;
        a0[t] = *(const short8*)(za);
        a1[t] = *(const short8*)(za + 32);
    }

    int row_r[RT][4];
#pragma unroll
    for (int t = 0; t < RT; ++t)
#pragma unroll
        for (int reg = 0; reg < 4; ++reg)
            row_r[t][reg] = rowbase + t * 16 + grp * 4 + reg;

    float mt[RT][4];
#pragma unroll
    for (int t = 0; t < RT; ++t)
#pragma unroll
        for (int reg = 0; reg < 4; ++reg) mt[t][reg] = __builtin_inff();

    /* ---- sweep A: per-row min over this segment's codes ---- */
#pragma unroll 2
    for (int ct = 0; ct < NCT; ++ct) {
        const int cr = ct * 16 + cl;
        const short8 b0 = *(const short8*)(ebS + (grp * SEGC + cr) * 8);
        const short8 b1 = *(const short8*)(ebS + ((grp + 4) * SEGC + cr) * 8);
        const float ne = neS[cr];
        f32x4 acc[RT];
#pragma unroll
        for (int t = 0; t < RT; ++t) {
            acc[t] = (f32x4){0.0f, 0.0f, 0.0f, 0.0f};
            acc[t] = __builtin_amdgcn_mfma_f32_16x16x32_bf16(a0[t], b0, acc[t], 0, 0, 0);
            acc[t] = __builtin_amdgcn_mfma_f32_16x16x32_bf16(a1[t], b1, acc[t], 0, 0, 0);
        }
#pragma unroll
        for (int t = 0; t < RT; ++t)
#pragma unroll
            for (int reg = 0; reg < 4; ++reg) {
                const float g = __builtin_fmaf(-2.0f, acc[t][reg], ne);
                mt[t][reg] = fminf(mt[t][reg], g);
            }
    }

    /* ---- allreduce across cl lanes, thr = min + mrg (in-place) ---- */
#pragma unroll
    for (int t = 0; t < RT; ++t)
#pragma unroll
        for (int reg = 0; reg < 4; ++reg) {
            float v = mt[t][reg];
            v = fminf(v, __shfl_xor(v, 1));
            v = fminf(v, __shfl_xor(v, 2));
            v = fminf(v, __shfl_xor(v, 4));
            v = fminf(v, __shfl_xor(v, 8));
            mt[t][reg] = v + mrg[row_r[t][reg]];
        }

    /* ---- sweep B: identical g~ bits; emit packed (g-key | code) ---- */
#pragma unroll 2
    for (int ct = 0; ct < NCT; ++ct) {
        const int cr = ct * 16 + cl;
        const short8 b0 = *(const short8*)(ebS + (grp * SEGC + cr) * 8);
        const short8 b1 = *(const short8*)(ebS + ((grp + 4) * SEGC + cr) * 8);
        const float ne = neS[cr];
        f32x4 acc[RT];
#pragma unroll
        for (int t = 0; t < RT; ++t) {
            acc[t] = (f32x4){0.0f, 0.0f, 0.0f, 0.0f};
            acc[t] = __builtin_amdgcn_mfma_f32_16x16x32_bf16(a0[t], b0, acc[t], 0, 0, 0);
            acc[t] = __builtin_amdgcn_mfma_f32_16x16x32_bf16(a1[t], b1, acc[t], 0, 0, 0);
        }
#pragma unroll
        for (int t = 0; t < RT; ++t)
#pragma unroll
            for (int reg = 0; reg < 4; ++reg) {
                const float g = __builtin_fmaf(-2.0f, acc[t][reg], ne);
                if (g <= mt[t][reg]) {
                    const unsigned idx = atomicAdd(&rowcnt[row_r[t][reg]], 1u);
                    if (idx < CAND_CAP)
                        candrow[(size_t)row_r[t][reg] * CAND_CAP + idx] =
                            (fmono(g) & KEYQ) | (unsigned)(c0 + cr);
                }
            }
    }
}

/* ---------- exact phase: prune by g-key, exact D on survivors ----------
   R16 regression fix: overflow rows are NOT serial-scanned here (one such
   lane = ~494K-cycle straggler wave = the whole 206us). They are deferred
   to the wave-cooperative vq_overflow kernel. */
__global__ __launch_bounds__(MAIN_BLOCK) void vq_exact(
    const float* __restrict__ z, const float* __restrict__ emb,
    const float* __restrict__ nE, const float* __restrict__ mrg,
    const unsigned* __restrict__ rowcnt, const unsigned* __restrict__ candrow,
    unsigned* __restrict__ ovl, unsigned* __restrict__ ovcnt,
    float* __restrict__ out, float* __restrict__ partials) {
    const int r = blockIdx.x * MAIN_BLOCK + threadIdx.x;
    const int b = r >> 12;
    const int l = r & (VQ_L - 1);
    const float* zp = z + ((size_t)b << 18) + l;

    float lsum = 0.0f;
    const unsigned cnt = rowcnt[r];
    if (cnt >= 1u && cnt <= (unsigned)CAND_CAP) {
        float szz;
        NP_SZZ_FROM_ZP(szz);

        /* pass 1: min quantized g-key over candidate set */
        unsigned kmin = 0xFFFFFFFFu;
        for (unsigned i = 0; i < cnt; ++i) {
            const unsigned key = candrow[(size_t)r * CAND_CAP + i];
            kmin = (key < kmin) ? key : kmin;
        }
        const float gthr = fmono_dec(kmin & KEYQ) + mrg[r];

        /* pass 2: exact D only for pruned survivors (~1.3/row) */
        unsigned long long best = ~0ull;
        for (unsigned i = 0; i < cnt; ++i) {
            const unsigned key = candrow[(size_t)r * CAND_CAP + i];
            if (fmono_dec(key & KEYQ) > gthr) continue;
            const int c = (int)(key & 1023u);
            const float* __restrict__ ec = emb + (c << 6);
            float acc = 0.0f;
#pragma unroll
            for (int k = 0; k < VQ_D; ++k)
                acc = __builtin_fmaf(zp[(size_t)k << 12], ec[k], acc);
            const float D = (szz - 2.0f * acc) + nE[c];
            const unsigned long long bk = ((unsigned long long)fmono(D) << 32) | (unsigned)c;
            best = (bk < best) ? bk : best;
        }
        const int bc = (int)(best & 1023u);

        const float* __restrict__ eb = emb + (bc << 6);
#pragma unroll
        for (int d = 0; d < VQ_D; ++d) {
            const float q = eb[d];
            const float zd = zp[(size_t)d << 12];
            out[((size_t)b << 18) + ((size_t)d << 12) + l] = q;
            const float df = q - zd;
            lsum = __builtin_fmaf(df, df, lsum);
        }
        out[VQ_ZQ + 1 + (size_t)r] = (float)bc;
    } else {
        /* defer to wave-cooperative overflow kernel */
        ovl[atomicAdd(ovcnt, 1u)] = (unsigned)r;
    }

#pragma unroll
    for (int off = 32; off > 0; off >>= 1)
        lsum += __shfl_down(lsum, off, 64);
    __shared__ float wsum[MAIN_BLOCK / 64];
    const int lane = threadIdx.x & 63;
    const int wid = threadIdx.x >> 6;
    if (lane == 0) wsum[wid] = lsum;
    __syncthreads();
    if (threadIdx.x == 0)
        partials[blockIdx.x] = (wsum[0] + wsum[1]) + (wsum[2] + wsum[3]);
}

/* ---------- overflow: one WAVE per deferred row, exact full scan ----------
   Fixed grid (graph-capture safe); trip count is device data. Lane scans 16
   codes with the bit-exact D formula; 64-bit key-min reduce = strict-<
   first-index. Wave-parallel epilogue. Loss via one atomicAdd slot (loss
   tolerance ~2%; ordering noise ~ulp). */
__global__ __launch_bounds__(256) void vq_overflow(
    const float* __restrict__ z, const float* __restrict__ emb,
    const float* __restrict__ nE, const unsigned* __restrict__ ovl,
    const unsigned* __restrict__ ovcnt, float* __restrict__ out,
    float* __restrict__ ovloss) {
    const int gw = (blockIdx.x * 256 + threadIdx.x) >> 6;  /* global wave id */
    const int lane = threadIdx.x & 63;
    const unsigned n = *ovcnt;
    for (unsigned i = gw; i < n; i += OV_WAVES) {
        const int r = (int)ovl[i];
        const int b = r >> 12;
        const int l = r & (VQ_L - 1);
        const float* zp = z + ((size_t)b << 18) + l;

        float szz;
        NP_SZZ_FROM_ZP(szz);   /* all lanes same row -> broadcast loads */

        unsigned long long best = ~0ull;
        for (int j = 0; j < 16; ++j) {
            const int c = lane * 16 + j;
            const float* __restrict__ ec = emb + (c << 6);
            float acc = 0.0f;
#pragma unroll
            for (int k = 0; k < VQ_D; ++k)
                acc = __builtin_fmaf(zp[(size_t)k << 12], ec[k], acc);
            const float D = (szz - 2.0f * acc) + nE[c];
            const unsigned long long bk = ((unsigned long long)fmono(D) << 32) | (unsigned)c;
            best = (bk < best) ? bk : best;
        }
#pragma unroll
        for (int off = 32; off > 0; off >>= 1) {
            const unsigned long long o = __shfl_xor(best, off, 64);
            best = (o < best) ? o : best;
        }
        const int bc = (int)(best & 1023u);

        /* wave-parallel epilogue: lane d handles element d */
        const float q = emb[(bc << 6) + lane];
        const float zd = zp[(size_t)lane << 12];
        out[((size_t)b << 18) + ((size_t)lane << 12) + l] = q;
        const float df = q - zd;
        float ls = df * df;
#pragma unroll
        for (int off = 32; off > 0; off >>= 1)
            ls += __shfl_down(ls, off, 64);
        if (lane == 0) {
            out[VQ_ZQ + 1 + (size_t)r] = (float)bc;
            atomicAdd(ovloss, ls);
        }
    }
}

__global__ void vq_final(const float* __restrict__ partials,
                         const float* __restrict__ ovloss, float* __restrict__ out) {
    if (threadIdx.x == 0 && blockIdx.x == 0) {
        float s = 0.0f;
        for (int i = 0; i < MAIN_GRID; ++i) s += partials[i];
        s += *ovloss;
        const float mse = s / (float)VQ_ZQ;
        out[VQ_ZQ] = mse + 0.25f * mse;
    }
}

/* ================= fallback path (round-8, validated, ~335us) ========== */
__global__ void vq_norme_fb(const float* __restrict__ emb, float* __restrict__ nEf) {
    const int c = blockIdx.x * blockDim.x + threadIdx.x;
    if (c >= VQ_N) return;
    const float* ec = emb + (c << 6);
    f32x16 zvA, zvB, zvC, zvD;
#pragma unroll
    for (int d = 0; d < 16; ++d) {
        zvA[d] = ec[d]; zvB[d] = ec[d + 16]; zvC[d] = ec[d + 32]; zvD[d] = ec[d + 48];
    }
    float s;
    NP_PAIRWISE64_SQ(s);
    nEf[c] = s;
}
__global__ __launch_bounds__(256, 4) void vq_dist_fb(
    const float* __restrict__ z, const float* __restrict__ emb,
    const float* __restrict__ nEf, float2* __restrict__ cand) {
    __shared__ float zs[VQ_D * 64];
    const int w = threadIdx.x >> 6;
    const int lane = threadIdx.x & 63;
    const int r = blockIdx.x * 64 + lane;
    const int b = r >> 12;
    const int l = r & (VQ_L - 1);
    const float* zp = z + ((size_t)b << 18) + l;
#pragma unroll
    for (int j = 0; j < 16; ++j) {
        const int d = (w << 4) + j;
        zs[d * 64 + lane] = zp[(size_t)d << 12];
    }
    __syncthreads();
    float a8[8];
#pragma unroll
    for (int j = 0; j < 8; ++j) {
        const float v = zs[j * 64 + lane];
        float s = v * v; asm volatile("" : "+v"(s)); a8[j] = s;
    }
#pragma unroll
    for (int i = 1; i < 8; ++i) {
#pragma unroll
        for (int j = 0; j < 8; ++j) {
            const float v = zs[(8 * i + j) * 64 + lane];
            float s = v * v; asm volatile("" : "+v"(s)); a8[j] += s;
        }
    }
    const float szz = ((a8[0] + a8[1]) + (a8[2] + a8[3])) + ((a8[4] + a8[5]) + (a8[6] + a8[7]));
    const int c0 = __builtin_amdgcn_readfirstlane(w) * 256;
    float best = __builtin_inff();
    int bc = c0;
    for (int t = 0; t < 256; t += 16) {
        float acc[16];
#pragma unroll
        for (int j = 0; j < 16; ++j) acc[j] = 0.0f;
#pragma unroll
        for (int kk = 0; kk < VQ_D; kk += 4) {
            const float z0 = zs[(kk + 0) * 64 + lane];
            const float z1 = zs[(kk + 1) * 64 + lane];
            const float z2 = zs[(kk + 2) * 64 + lane];
            const float z3 = zs[(kk + 3) * 64 + lane];
#pragma unroll
            for (int j = 0; j < 16; ++j) {
                const float* __restrict__ ec = emb + ((c0 + t + j) << 6) + kk;
                acc[j] = __builtin_fmaf(z0, ec[0], acc[j]);
                acc[j] = __builtin_fmaf(z1, ec[1], acc[j]);
                acc[j] = __builtin_fmaf(z2, ec[2], acc[j]);
                acc[j] = __builtin_fmaf(z3, ec[3], acc[j]);
            }
        }
#pragma unroll
        for (int j = 0; j < 16; ++j) {
            const int c = c0 + t + j;
            const float dist = (szz - 2.0f * acc[j]) + nEf[c];
            if (dist < best) { best = dist; bc = c; }
        }
    }
    cand[(size_t)w * VQ_R + r] = make_float2(best, (float)bc);
}
__global__ __launch_bounds__(MAIN_BLOCK) void vq_epilogue_fb(
    const float* __restrict__ z, const float* __restrict__ emb,
    const float2* __restrict__ cand, float* __restrict__ out,
    float* __restrict__ partials) {
    const int r = blockIdx.x * MAIN_BLOCK + threadIdx.x;
    const int b = r >> 12;
    const int l = r & (VQ_L - 1);
    float best = __builtin_inff();
    int bc = 0;
#pragma unroll
    for (int seg = 0; seg < 4; ++seg) {
        const float2 cd = cand[(size_t)seg * VQ_R + r];
        if (cd.x < best) { best = cd.x; bc = (int)cd.y; }
    }
    const float* zp = z + ((size_t)b << 18) + l;
    const float* __restrict__ eb = emb + (bc << 6);
    float lsum = 0.0f;
#pragma unroll
    for (int d = 0; d < VQ_D; ++d) {
        const float q = eb[d];
        const float zd = zp[(size_t)d << 12];
        out[((size_t)b << 18) + ((size_t)d << 12) + l] = q;
        const float df = q - zd;
        lsum = __builtin_fmaf(df, df, lsum);
    }
    out[VQ_ZQ + 1 + (size_t)r] = (float)bc;
#pragma unroll
    for (int off = 32; off > 0; off >>= 1)
        lsum += __shfl_down(lsum, off, 64);
    __shared__ float wsum[MAIN_BLOCK / 64];
    const int lane = threadIdx.x & 63;
    const int wid = threadIdx.x >> 6;
    if (lane == 0) wsum[wid] = lsum;
    __syncthreads();
    if (threadIdx.x == 0)
        partials[blockIdx.x] = (wsum[0] + wsum[1]) + (wsum[2] + wsum[3]);
}
__global__ void vq_final_fb(const float* __restrict__ partials, float* __restrict__ out) {
    if (threadIdx.x == 0 && blockIdx.x == 0) {
        float s = 0.0f;
        for (int i = 0; i < MAIN_GRID; ++i) s += partials[i];
        const float mse = s / (float)VQ_ZQ;
        out[VQ_ZQ] = mse + 0.25f * mse;
    }
}

/* ================= launch ================= */
extern "C" void kernel_launch(void* const* d_in, const int* in_sizes, int n_in,
                              void* d_out, int out_size, void* d_ws, size_t ws_size,
                              hipStream_t stream) {
    const float* z   = (const float*)d_in[0];
    const float* emb = (const float*)d_in[1];
    float* out = (float*)d_out;
    char* ws = (char*)d_ws;

    /* layout (16B-aligned) */
    unsigned short* z_bf   = (unsigned short*)(ws);                       /* 16777216 B */
    unsigned short* emb_bf = (unsigned short*)(ws + 16777216);            /*   131072 B */
    unsigned*       candrw = (unsigned*)(ws + 16908288);                  /*  8388608 B */
    float*          mrg    = (float*)(ws + 25296896);                     /*   524288 B */
    unsigned*       rowcnt = (unsigned*)(ws + 25821184);                  /*   524288 B */
    unsigned*       ovl    = (unsigned*)(ws + 26345472);                  /*   524288 B */
    float*          nE     = (float*)(ws + 26869760);                     /*     4096 B */
    float*          parts  = (float*)(ws + 26873856);                     /*     2048 B */
    unsigned*       nEmax  = (unsigned*)(ws + 26875904);                  /*        4 B */
    unsigned*       ovcnt  = (unsigned*)(ws + 26875908);                  /*        4 B */
    float*          ovloss = (float*)(ws + 26875912);                     /*        4 B */
    const size_t need = 26875968;

    if (ws_size >= need) {
        vq_init<<<dim3(512), dim3(256), 0, stream>>>(rowcnt, nEmax, ovcnt, ovloss);
        vq_prep_emb<<<dim3(4), dim3(256), 0, stream>>>(emb, nE, emb_bf, nEmax);
        vq_prep_z<<<dim3(512), dim3(256), 0, stream>>>(z, nEmax, z_bf, mrg);
        vq_screen<<<dim3(VQ_R / 256, NSEG), dim3(256), 0, stream>>>(
            z_bf, emb_bf, nE, mrg, rowcnt, candrw);
        vq_exact<<<dim3(MAIN_GRID), dim3(MAIN_BLOCK), 0, stream>>>(
            z, emb, nE, mrg, rowcnt, candrw, ovl, ovcnt, out, parts);
        vq_overflow<<<dim3(OV_WAVES / 4), dim3(256), 0, stream>>>(
            z, emb, nE, ovl, ovcnt, out, ovloss);
        vq_final<<<dim3(1), dim3(64), 0, stream>>>(parts, ovloss, out);
    } else {
        /* validated round-8 fallback (~4.2 MB ws) */
        float* nEf = (float*)ws;
        float* partials = nEf + VQ_N;
        float2* cand = (float2*)(partials + MAIN_GRID);
        vq_norme_fb<<<dim3(4), dim3(256), 0, stream>>>(emb, nEf);
        vq_dist_fb<<<dim3(VQ_R / 64), dim3(256), 0, stream>>>(z, emb, nEf, cand);
        vq_epilogue_fb<<<dim3(MAIN_GRID), dim3(MAIN_BLOCK), 0, stream>>>(z, emb, cand, out, partials);
        vq_final_fb<<<dim3(1), dim3(64), 0, stream>>>(partials, out);
    }
}